// Round 4
// baseline (2132.453 us; speedup 1.0000x reference)
//
#include <hip/hip_runtime.h>
#include <hip/hip_bf16.h>
#include <hip/hip_cooperative_groups.h>

#define LL 12
#define BB 32
#define SS 197
#define DV 768
#define DD 512
#define CC 48
#define VV 49
#define LOSS_DEN 786432.0f

typedef unsigned short u16;
typedef unsigned int u32;
using bf16x8 = __attribute__((ext_vector_type(8))) __bf16;
using f32x4 = __attribute__((ext_vector_type(4))) float;
using u16x8 = __attribute__((ext_vector_type(8))) u16;

__device__ __forceinline__ u16 bf16h(float x) {
    u32 u = __builtin_bit_cast(u32, x);
    return (u16)((u + 0x7FFFu + ((u >> 16) & 1u)) >> 16);
}
__device__ __forceinline__ float bf2f(u16 h) {
    u32 u = ((u32)h) << 16;
    return __builtin_bit_cast(float, u);
}
__device__ __forceinline__ f32x4 mfma16(bf16x8 a, bf16x8 b, f32x4 c) {
    return __builtin_amdgcn_mfma_f32_16x16x32_bf16(a, b, c, 0, 0, 0);
}
__device__ __forceinline__ void gl_lds16(const void* g, void* s) {
    __builtin_amdgcn_global_load_lds((const __attribute__((address_space(1))) u32*)g,
                                     (__attribute__((address_space(3))) u32*)s, 16, 0, 0);
}

// ---------------------------------------------------------------------------
// Pool + bf16 hi/lo split of X
__global__ __launch_bounds__(256) void pool_split(const float* __restrict__ feats,
                                                  u16* __restrict__ Xh, u16* __restrict__ Xl) {
    int row = blockIdx.x;
    int t = threadIdx.x;
    int v = row % VV;
    int lb = row / VV;
    const float* f = feats + (size_t)lb * SS * DV;
    for (int d = t; d < DV; d += 256) {
        float val;
        if (v == 0) {
            val = f[d];
        } else {
            int i = v - 1;
            int s = (i * 196) / 48;
            int e = ((i + 1) * 196 + 47) / 48;
            float acc = 0.0f;
            for (int j = s; j < e; ++j) acc += f[(size_t)(1 + j) * DV + d];
            val = acc / (float)(e - s);
        }
        u16 h = bf16h(val);
        Xh[(size_t)row * DV + d] = h;
        Xl[(size_t)row * DV + d] = bf16h(val - bf2f(h));
    }
}

// Combined weight splits
#define NL (512 * 768)
#define NG (512 * 1536)
#define NU (512 * 1024)
__global__ __launch_bounds__(256) void wsplit_all(const float* __restrict__ Wl,
                                                  const float* __restrict__ Wg,
                                                  const float* __restrict__ Wu,
                                                  u16* Wlh, u16* Wll, u16* Wgh, u16* Wgl,
                                                  u16* Wuh, u16* Wul) {
    int i = blockIdx.x * 256 + threadIdx.x;
    float v;
    u16 *ph, *pl;
    int j;
    if (i < NL) { v = Wl[i]; ph = Wlh; pl = Wll; j = i; }
    else if (i < NL + NG) { j = i - NL; v = Wg[j]; ph = Wgh; pl = Wgl; }
    else { j = i - NL - NG; v = Wu[j]; ph = Wuh; pl = Wul; }
    u16 hh = bf16h(v);
    ph[j] = hh;
    pl[j] = bf16h(v - bf2f(hh));
}

// ---------------------------------------------------------------------------
// f32 GEMM for ctx projection with bf16 plane epilogue.
__global__ __launch_bounds__(256) void gemm_nt(const float* __restrict__ A, int lda,
                                               const float* __restrict__ W, int K,
                                               float* __restrict__ Cout,
                                               u16* __restrict__ Ch, u16* __restrict__ Cl) {
    __shared__ float As[32][65];
    __shared__ float Bs[32][65];
    int t = threadIdx.x;
    int m0 = blockIdx.x * 64;
    int n0 = blockIdx.y * 64;
    int r = t >> 2;
    int kc = (t & 3) * 8;
    int tx = t & 15, ty = t >> 4;
    float acc[4][4] = {};
    for (int k0 = 0; k0 < K; k0 += 32) {
        const float4* pa = (const float4*)(A + (size_t)(m0 + r) * lda + k0 + kc);
        float4 a0 = pa[0], a1 = pa[1];
        const float4* pw = (const float4*)(W + (size_t)(n0 + r) * K + k0 + kc);
        float4 w0 = pw[0], w1 = pw[1];
        As[kc + 0][r] = a0.x; As[kc + 1][r] = a0.y; As[kc + 2][r] = a0.z; As[kc + 3][r] = a0.w;
        As[kc + 4][r] = a1.x; As[kc + 5][r] = a1.y; As[kc + 6][r] = a1.z; As[kc + 7][r] = a1.w;
        Bs[kc + 0][r] = w0.x; Bs[kc + 1][r] = w0.y; Bs[kc + 2][r] = w0.z; Bs[kc + 3][r] = w0.w;
        Bs[kc + 4][r] = w1.x; Bs[kc + 5][r] = w1.y; Bs[kc + 6][r] = w1.z; Bs[kc + 7][r] = w1.w;
        __syncthreads();
#pragma unroll
        for (int kk = 0; kk < 32; ++kk) {
            float a[4], b[4];
#pragma unroll
            for (int i = 0; i < 4; ++i) { a[i] = As[kk][ty * 4 + i]; b[i] = Bs[kk][tx * 4 + i]; }
#pragma unroll
            for (int i = 0; i < 4; ++i)
#pragma unroll
                for (int j = 0; j < 4; ++j) acc[i][j] += a[i] * b[j];
        }
        __syncthreads();
    }
#pragma unroll
    for (int i = 0; i < 4; ++i) {
        int m = m0 + ty * 4 + i;
#pragma unroll
        for (int j = 0; j < 4; ++j) {
            int n = n0 + tx * 4 + j;
            float v = acc[i][j];
            size_t o = (size_t)m * DD + n;
            Cout[o] = v;
            u16 hh = bf16h(v);
            Ch[o] = hh;
            Cl[o] = bf16h(v - bf2f(hh));
        }
    }
}

// ---------------------------------------------------------------------------
// vt = X @ W_lin.T + b_lin  (bf16x3 MFMA), emits bf16 hi/lo planes.
__global__ __launch_bounds__(256, 2) void vt_gemm(const u16* __restrict__ Xh, const u16* __restrict__ Xl,
                                                  const u16* __restrict__ Wh, const u16* __restrict__ Wl,
                                                  const float* __restrict__ bias,
                                                  u16* __restrict__ vthp, u16* __restrict__ vtlp) {
    __shared__ u16 sm[24576];
    int tid = threadIdx.x;
    int w = tid >> 6, l = tid & 63, lr = l & 15, ls = l >> 4;
    int m0 = blockIdx.x * 128, n0 = blockIdx.y * 64;
    f32x4 acc[2][4];
#pragma unroll
    for (int i = 0; i < 2; ++i)
#pragma unroll
        for (int j = 0; j < 4; ++j) acc[i][j] = f32x4{0.f, 0.f, 0.f, 0.f};

    auto stage = [&](u16* dst, int k0) {
#pragma unroll
        for (int is = 0; is < 6; ++is) {
            int q = is * 256 + tid;
            const u16* src;
            int off;
            if (is < 2)      { int qr = q;        int row = qr >> 2, sl = qr & 3; src = Xh + (size_t)(m0 + row) * DV + k0 + ((sl ^ ((row >> 1) & 3)) << 3); off = qr * 8; }
            else if (is < 4) { int qr = q - 512;  int row = qr >> 2, sl = qr & 3; src = Xl + (size_t)(m0 + row) * DV + k0 + ((sl ^ ((row >> 1) & 3)) << 3); off = 4096 + qr * 8; }
            else if (is < 5) { int qr = q - 1024; int row = qr >> 2, sl = qr & 3; src = Wh + (size_t)(n0 + row) * DV + k0 + ((sl ^ ((row >> 1) & 3)) << 3); off = 8192 + qr * 8; }
            else             { int qr = q - 1280; int row = qr >> 2, sl = qr & 3; src = Wl + (size_t)(n0 + row) * DV + k0 + ((sl ^ ((row >> 1) & 3)) << 3); off = 10240 + qr * 8; }
            gl_lds16(src, dst + off);
        }
    };

    stage(sm, 0);
    __syncthreads();
    for (int t = 0; t < 24; ++t) {
        u16* cur = sm + ((t & 1) ? 12288 : 0);
        u16* nxt = sm + ((t & 1) ? 0 : 12288);
        if (t + 1 < 24) stage(nxt, (t + 1) * 32);
        bf16x8 ah[2], al2[2], bh[4], bl2[4];
#pragma unroll
        for (int rf = 0; rf < 2; ++rf) {
            int row = 32 * w + 16 * rf + lr;
            int ro = row * 32 + ((ls ^ ((row >> 1) & 3)) << 3);
            ah[rf] = *(const bf16x8*)(cur + ro);
            al2[rf] = *(const bf16x8*)(cur + 4096 + ro);
        }
#pragma unroll
        for (int cf = 0; cf < 4; ++cf) {
            int n = 16 * cf + lr;
            int no = n * 32 + ((ls ^ ((n >> 1) & 3)) << 3);
            bh[cf] = *(const bf16x8*)(cur + 8192 + no);
            bl2[cf] = *(const bf16x8*)(cur + 10240 + no);
        }
#pragma unroll
        for (int rf = 0; rf < 2; ++rf)
#pragma unroll
            for (int cf = 0; cf < 4; ++cf) {
                acc[rf][cf] = mfma16(ah[rf], bh[cf], acc[rf][cf]);
                acc[rf][cf] = mfma16(ah[rf], bl2[cf], acc[rf][cf]);
                acc[rf][cf] = mfma16(al2[rf], bh[cf], acc[rf][cf]);
            }
        __syncthreads();
    }
#pragma unroll
    for (int rf = 0; rf < 2; ++rf)
#pragma unroll
        for (int cf = 0; cf < 4; ++cf)
#pragma unroll
            for (int r = 0; r < 4; ++r) {
                int row = m0 + 32 * w + 16 * rf + 4 * ls + r;
                int col = n0 + 16 * cf + lr;
                float v = acc[rf][cf][r] + bias[col];
                size_t o = (size_t)row * DD + col;
                u16 hh = bf16h(v);
                vthp[o] = hh;
                vtlp[o] = bf16h(v - bf2f(hh));
            }
}

// ---------------------------------------------------------------------------
__global__ __launch_bounds__(256) void init_q_loss(const float* __restrict__ ce,
                                                   u16* __restrict__ qh, u16* __restrict__ ql,
                                                   float* __restrict__ loss) {
    int i = blockIdx.x * 256 + threadIdx.x;
    float v = ce[i % (CC * DD)];
    u16 hh = bf16h(v);
    qh[i] = hh;
    ql[i] = bf16h(v - bf2f(hh));
    if (i == 0) loss[0] = 0.0f;
}

// ---------------------------------------------------------------------------
// Cooperative mega-kernel: 192 blocks x 256 threads, whole 12-layer scan + final.
struct ScanP {
    u16 *qah, *qal, *qbh, *qbl;
    const u16 *vth, *vtl, *ch, *cl;
    const u16 *Wgh, *Wgl, *Wuh, *Wul;
    const float *bg, *bu;
    float *f0, *f1;
    u16 *fh, *fl;
    float *loss;
    const float *ce, *Wcls, *bcls;
    float *out;
};

__device__ void attn_phase(const u16* __restrict__ qch, const u16* __restrict__ qcl,
                           const u16* __restrict__ vthL, const u16* __restrict__ vtlL,
                           float* __restrict__ fcur, const float* __restrict__ fprev,
                           u16* __restrict__ fh, u16* __restrict__ fl,
                           float* __restrict__ loss, bool do_loss) {
    int wgid = blockIdx.x * 4 + (threadIdx.x >> 6);
    int lane = threadIdx.x & 63;
    int b = wgid / 24;
    int r0 = b * CC + (wgid % 24) * 2;
    size_t o0 = (size_t)r0 * DD + lane * 8;
    u16x8 h0 = *(const u16x8*)(qch + o0), g0 = *(const u16x8*)(qcl + o0);
    u16x8 h1 = *(const u16x8*)(qch + o0 + DD), g1 = *(const u16x8*)(qcl + o0 + DD);
    float q0v[8], q1v[8];
#pragma unroll
    for (int j = 0; j < 8; ++j) {
        q0v[j] = bf2f(h0[j]) + bf2f(g0[j]);
        q1v[j] = bf2f(h1[j]) + bf2f(g1[j]);
    }
    const u16* vh = vthL + (size_t)b * VV * DD + lane * 8;
    const u16* vl = vtlL + (size_t)b * VV * DD + lane * 8;
    float m0 = -3e38f, m1 = -3e38f, s0 = 0.f, s1 = 0.f;
    float a0[8] = {}, a1[8] = {};
    for (int v = 0; v < VV; ++v) {
        u16x8 rh = *(const u16x8*)(vh + v * DD);
        u16x8 rl = *(const u16x8*)(vl + v * DD);
        float rv[8];
#pragma unroll
        for (int j = 0; j < 8; ++j) rv[j] = bf2f(rh[j]) + bf2f(rl[j]);
        float p0 = 0.f, p1 = 0.f;
#pragma unroll
        for (int j = 0; j < 8; ++j) { p0 += q0v[j] * rv[j]; p1 += q1v[j] * rv[j]; }
#pragma unroll
        for (int off = 32; off > 0; off >>= 1) { p0 += __shfl_xor(p0, off); p1 += __shfl_xor(p1, off); }
        float nm0 = fmaxf(m0, p0);
        float sc0 = __expf(m0 - nm0), w0 = __expf(p0 - nm0);
        s0 = s0 * sc0 + w0;
        float nm1 = fmaxf(m1, p1);
        float sc1 = __expf(m1 - nm1), w1 = __expf(p1 - nm1);
        s1 = s1 * sc1 + w1;
#pragma unroll
        for (int j = 0; j < 8; ++j) {
            a0[j] = a0[j] * sc0 + w0 * rv[j];
            a1[j] = a1[j] * sc1 + w1 * rv[j];
        }
        m0 = nm0;
        m1 = nm1;
    }
    float inv0 = 1.0f / s0, inv1 = 1.0f / s1;
    float d2 = 0.f;
    float f0v[8], f1v[8];
    u16x8 oh0, ol0, oh1, ol1;
#pragma unroll
    for (int j = 0; j < 8; ++j) {
        float f = a0[j] * inv0;
        f0v[j] = f;
        u16 hh = bf16h(f);
        oh0[j] = hh;
        ol0[j] = bf16h(f - bf2f(hh));
        float f2 = a1[j] * inv1;
        f1v[j] = f2;
        u16 h2 = bf16h(f2);
        oh1[j] = h2;
        ol1[j] = bf16h(f2 - bf2f(h2));
    }
    *(float4*)(fcur + o0) = float4{f0v[0], f0v[1], f0v[2], f0v[3]};
    *(float4*)(fcur + o0 + 4) = float4{f0v[4], f0v[5], f0v[6], f0v[7]};
    *(float4*)(fcur + o0 + DD) = float4{f1v[0], f1v[1], f1v[2], f1v[3]};
    *(float4*)(fcur + o0 + DD + 4) = float4{f1v[4], f1v[5], f1v[6], f1v[7]};
    *(u16x8*)(fh + o0) = oh0;
    *(u16x8*)(fl + o0) = ol0;
    *(u16x8*)(fh + o0 + DD) = oh1;
    *(u16x8*)(fl + o0 + DD) = ol1;
    if (do_loss) {
#pragma unroll
        for (int j = 0; j < 8; ++j) {
            float d = f0v[j] - fprev[o0 + j];
            d2 += d * d;
            float e = f1v[j] - fprev[o0 + DD + j];
            d2 += e * e;
        }
#pragma unroll
        for (int off = 32; off > 0; off >>= 1) d2 += __shfl_xor(d2, off);
        if (lane == 0) atomicAdd(loss, d2);
    }
}

__device__ void gate_phase(u16* sm, const u16* __restrict__ fhp, const u16* __restrict__ flp,
                           const u16* __restrict__ qhp, const u16* __restrict__ qlp,
                           const u16* __restrict__ chp, const u16* __restrict__ clp,
                           const u16* __restrict__ Wgh, const u16* __restrict__ Wgl,
                           const u16* __restrict__ Wuh, const u16* __restrict__ Wul,
                           const float* __restrict__ bg, const float* __restrict__ bu,
                           u16* __restrict__ qoh, u16* __restrict__ qol) {
    int tid = threadIdx.x;
    int w = tid >> 6, l = tid & 63, lr = l & 15, ls = l >> 4;
    int wr = w >> 1, wc = w & 1;
    int m0 = (blockIdx.x >> 3) * 64, n0 = (blockIdx.x & 7) * 64;
    f32x4 ag[2][2], au[2][2];
#pragma unroll
    for (int i = 0; i < 2; ++i)
#pragma unroll
        for (int j = 0; j < 2; ++j) { ag[i][j] = f32x4{0.f, 0.f, 0.f, 0.f}; au[i][j] = f32x4{0.f, 0.f, 0.f, 0.f}; }

    auto stage = [&](u16* dst, int k0) {
        int q = tid, row = q >> 2, sl = q & 3;
        int kk = ((sl ^ ((row >> 1) & 3)) << 3);
        int mrow = m0 + row, nrow = n0 + row;
        const u16 *sa, *sb;
        if (k0 < 512)       { sa = fhp + (size_t)mrow * DD + k0 + kk;          sb = flp + (size_t)mrow * DD + k0 + kk; }
        else if (k0 < 1024) { sa = qhp + (size_t)mrow * DD + (k0 - 512) + kk;  sb = qlp + (size_t)mrow * DD + (k0 - 512) + kk; }
        else { int brow = mrow / CC; sa = chp + (size_t)brow * DD + (k0 - 1024) + kk; sb = clp + (size_t)brow * DD + (k0 - 1024) + kk; }
        gl_lds16(sa, dst + q * 8);
        gl_lds16(sb, dst + 2048 + q * 8);
        gl_lds16(Wgh + (size_t)nrow * 1536 + k0 + kk, dst + 4096 + q * 8);
        gl_lds16(Wgl + (size_t)nrow * 1536 + k0 + kk, dst + 6144 + q * 8);
        if (k0 < 1024) {
            gl_lds16(Wuh + (size_t)nrow * 1024 + k0 + kk, dst + 8192 + q * 8);
            gl_lds16(Wul + (size_t)nrow * 1024 + k0 + kk, dst + 10240 + q * 8);
        }
    };

    stage(sm, 0);
    __syncthreads();
    for (int t = 0; t < 48; ++t) {
        u16* cur = sm + ((t & 1) ? 12288 : 0);
        u16* nxt = sm + ((t & 1) ? 0 : 12288);
        if (t + 1 < 48) stage(nxt, (t + 1) * 32);
        bf16x8 a_h[2], a_l[2], g_h[2], g_l[2], u_h[2], u_l[2];
#pragma unroll
        for (int rf = 0; rf < 2; ++rf) {
            int arow = 32 * wr + 16 * rf + lr;
            int ao = arow * 32 + ((ls ^ ((arow >> 1) & 3)) << 3);
            a_h[rf] = *(const bf16x8*)(cur + ao);
            a_l[rf] = *(const bf16x8*)(cur + 2048 + ao);
        }
#pragma unroll
        for (int cf = 0; cf < 2; ++cf) {
            int n = 32 * wc + 16 * cf + lr;
            int no = n * 32 + ((ls ^ ((n >> 1) & 3)) << 3);
            g_h[cf] = *(const bf16x8*)(cur + 4096 + no);
            g_l[cf] = *(const bf16x8*)(cur + 6144 + no);
            if (t < 32) {
                u_h[cf] = *(const bf16x8*)(cur + 8192 + no);
                u_l[cf] = *(const bf16x8*)(cur + 10240 + no);
            }
        }
#pragma unroll
        for (int rf = 0; rf < 2; ++rf)
#pragma unroll
            for (int cf = 0; cf < 2; ++cf) {
                ag[rf][cf] = mfma16(a_h[rf], g_h[cf], ag[rf][cf]);
                ag[rf][cf] = mfma16(a_h[rf], g_l[cf], ag[rf][cf]);
                ag[rf][cf] = mfma16(a_l[rf], g_h[cf], ag[rf][cf]);
                if (t < 32) {
                    au[rf][cf] = mfma16(a_h[rf], u_h[cf], au[rf][cf]);
                    au[rf][cf] = mfma16(a_h[rf], u_l[cf], au[rf][cf]);
                    au[rf][cf] = mfma16(a_l[rf], u_h[cf], au[rf][cf]);
                }
            }
        __syncthreads();
    }
#pragma unroll
    for (int rf = 0; rf < 2; ++rf)
#pragma unroll
        for (int cf = 0; cf < 2; ++cf)
#pragma unroll
            for (int r = 0; r < 4; ++r) {
                int row = m0 + 32 * wr + 16 * rf + 4 * ls + r;
                int col = n0 + 32 * wc + 16 * cf + lr;
                float g = 1.0f / (1.0f + __expf(-(ag[rf][cf][r] + bg[col])));
                float u = tanhf(au[rf][cf][r] + bu[col]);
                size_t o = (size_t)row * DD + col;
                float qv = bf2f(qhp[o]) + bf2f(qlp[o]);
                float qo = g * qv + (1.0f - g) * u;
                u16 hh = bf16h(qo);
                qoh[o] = hh;
                qol[o] = bf16h(qo - bf2f(hh));
            }
}

__device__ void final_phase(const float* __restrict__ fuse_last, const float* __restrict__ ce,
                            const float* __restrict__ W_cls, const float* __restrict__ b_cls,
                            const float* __restrict__ loss_acc, float* __restrict__ out,
                            float* invn, float* img) {
    int b = blockIdx.x;
    int t = threadIdx.x;
    int w = t >> 6, lane = t & 63;
    const float* fb = fuse_last + (size_t)b * CC * DD;
    for (int c = w; c < CC; c += 4) {
        const float* fr = fb + (size_t)c * DD + lane * 8;
        float4 a0 = *(const float4*)fr;
        float4 a1 = *(const float4*)(fr + 4);
        float ss = a0.x * a0.x + a0.y * a0.y + a0.z * a0.z + a0.w * a0.w +
                   a1.x * a1.x + a1.y * a1.y + a1.z * a1.z + a1.w * a1.w;
#pragma unroll
        for (int off = 32; off > 0; off >>= 1) ss += __shfl_xor(ss, off);
        if (lane == 0) invn[c] = 1.0f / fmaxf(sqrtf(ss), 1e-12f);
    }
    __syncthreads();
    for (int g = w; g < CC; g += 4) {
        int k = g / 6;
        const float* ar = ce + (size_t)g * DD + lane * 8;
        float4 c0 = *(const float4*)ar;
        float4 c1 = *(const float4*)(ar + 4);
        float av[8] = {c0.x, c0.y, c0.z, c0.w, c1.x, c1.y, c1.z, c1.w};
        float accp = 0.0f;
        for (int p = 0; p < 6; ++p) {
            int row = k * 6 + p;
            const float* fr = fb + (size_t)row * DD + lane * 8;
            float4 f0 = *(const float4*)fr;
            float4 f1 = *(const float4*)(fr + 4);
            float fv[8] = {f0.x, f0.y, f0.z, f0.w, f1.x, f1.y, f1.z, f1.w};
            float d = 0.0f;
#pragma unroll
            for (int j = 0; j < 8; ++j) d += fv[j] * av[j];
            accp += d * invn[row];
        }
#pragma unroll
        for (int off = 32; off > 0; off >>= 1) accp += __shfl_xor(accp, off);
        if (lane == 0) img[g] = accp * (100.0f / 6.0f);
    }
    __syncthreads();
    if (t < CC) out[BB * 7 + b * CC + t] = img[t];
    if (t < 7) {
        float sacc = b_cls[t];
        for (int c = 0; c < CC; ++c) sacc += img[c] * W_cls[t * CC + c];
        out[b * 7 + t] = sacc;
    }
    if (b == 0 && t == 0) out[BB * 7 + BB * CC] = loss_acc[0] * (1.0f / LOSS_DEN);
}

__global__ __launch_bounds__(256, 1) void scan_all(ScanP P) {
    __shared__ u16 sm[24576];
    __shared__ float invn[CC];
    __shared__ float img[CC];
    cooperative_groups::grid_group grid = cooperative_groups::this_grid();
    u16* qph[2] = {P.qah, P.qbh};
    u16* qpl[2] = {P.qal, P.qbl};
    int qc = 0;
    for (int l = 0; l < LL; ++l) {
        float* fcur = (l & 1) ? P.f1 : P.f0;
        const float* fprev = (l & 1) ? P.f0 : P.f1;
        attn_phase(qph[qc], qpl[qc],
                   P.vth + (size_t)l * BB * VV * DD, P.vtl + (size_t)l * BB * VV * DD,
                   fcur, fprev, P.fh, P.fl, P.loss, l > 0);
        __threadfence();
        grid.sync();
        if (l < LL - 1) {
            gate_phase(sm, P.fh, P.fl, qph[qc], qpl[qc],
                       P.ch + (size_t)l * BB * DD, P.cl + (size_t)l * BB * DD,
                       P.Wgh, P.Wgl, P.Wuh, P.Wul, P.bg, P.bu,
                       qph[qc ^ 1], qpl[qc ^ 1]);
            qc ^= 1;
            __threadfence();
            grid.sync();
        }
    }
    if (blockIdx.x < BB)
        final_phase((LL - 1) & 1 ? P.f1 : P.f0, P.ce, P.Wcls, P.bcls, P.loss, P.out, invn, img);
}

// ---------------------------------------------------------------------------
extern "C" void kernel_launch(void* const* d_in, const int* in_sizes, int n_in,
                              void* d_out, int out_size, void* d_ws, size_t ws_size,
                              hipStream_t stream) {
    const float* feats = (const float*)d_in[0];
    const float* ce = (const float*)d_in[1];
    const float* W_lin = (const float*)d_in[2];
    const float* b_lin = (const float*)d_in[3];
    const float* W_proj = (const float*)d_in[4];
    const float* W_gate = (const float*)d_in[5];
    const float* b_gate = (const float*)d_in[6];
    const float* W_upd = (const float*)d_in[7];
    const float* b_upd = (const float*)d_in[8];
    const float* W_cls = (const float*)d_in[9];
    const float* b_cls = (const float*)d_in[10];
    float* out = (float*)d_out;

    char* base = (char*)d_ws;
    size_t off = 0;
    auto alloc = [&](size_t bytes) -> char* {
        char* r = base + off;
        off += (bytes + 255) & ~(size_t)255;
        return r;
    };
    u16* Xh = (u16*)alloc((size_t)LL * BB * VV * DV * 2);
    u16* Xl = (u16*)alloc((size_t)LL * BB * VV * DV * 2);
    u16* vth = (u16*)alloc((size_t)LL * BB * VV * DD * 2);
    u16* vtl = (u16*)alloc((size_t)LL * BB * VV * DD * 2);
    float* ctx = (float*)alloc((size_t)LL * BB * DD * 4);
    float* fbuf0 = (float*)alloc((size_t)BB * CC * DD * 4);
    float* fbuf1 = (float*)alloc((size_t)BB * CC * DD * 4);
    float* loss = (float*)alloc(256);
    u16* Wlh = (u16*)alloc((size_t)NL * 2);
    u16* Wll = (u16*)alloc((size_t)NL * 2);
    u16* Wgh = (u16*)alloc((size_t)NG * 2);
    u16* Wgl = (u16*)alloc((size_t)NG * 2);
    u16* Wuh = (u16*)alloc((size_t)NU * 2);
    u16* Wul = (u16*)alloc((size_t)NU * 2);
    u16* ch = (u16*)alloc((size_t)LL * BB * DD * 2);
    u16* cl = (u16*)alloc((size_t)LL * BB * DD * 2);
    u16* fh = (u16*)alloc((size_t)BB * CC * DD * 2);
    u16* fl = (u16*)alloc((size_t)BB * CC * DD * 2);
    u16* qah = (u16*)alloc((size_t)BB * CC * DD * 2);
    u16* qal = (u16*)alloc((size_t)BB * CC * DD * 2);
    u16* qbh = (u16*)alloc((size_t)BB * CC * DD * 2);
    u16* qbl = (u16*)alloc((size_t)BB * CC * DD * 2);

    // Precompute
    pool_split<<<LL * BB * VV, 256, 0, stream>>>(feats, Xh, Xl);
    wsplit_all<<<(NL + NG + NU) / 256, 256, 0, stream>>>(W_lin, W_gate, W_upd, Wlh, Wll, Wgh, Wgl, Wuh, Wul);
    {
        dim3 g(LL * BB / 64, DD / 64);
        gemm_nt<<<g, 256, 0, stream>>>(feats, SS * DV, W_proj, DV, ctx, ch, cl);
    }
    init_q_loss<<<(BB * CC * DD) / 256, 256, 0, stream>>>(ce, qah, qal, loss);
    {
        dim3 g(147, 8);
        vt_gemm<<<g, 256, 0, stream>>>(Xh, Xl, Wlh, Wll, b_lin, vth, vtl);
    }

    // Cooperative scan (12 layers + final epilogue)
    ScanP P;
    P.qah = qah; P.qal = qal; P.qbh = qbh; P.qbl = qbl;
    P.vth = vth; P.vtl = vtl; P.ch = ch; P.cl = cl;
    P.Wgh = Wgh; P.Wgl = Wgl; P.Wuh = Wuh; P.Wul = Wul;
    P.bg = b_gate; P.bu = b_upd;
    P.f0 = fbuf0; P.f1 = fbuf1;
    P.fh = fh; P.fl = fl;
    P.loss = loss;
    P.ce = ce; P.Wcls = W_cls; P.bcls = b_cls;
    P.out = out;
    void* kargs[] = {(void*)&P};
    hipLaunchCooperativeKernel((const void*)scan_all, dim3(192), dim3(256), kargs, 0, stream);
}

// Round 5
// 1037.393 us; speedup vs baseline: 2.0556x; 2.0556x over previous
//
#include <hip/hip_runtime.h>
#include <hip/hip_bf16.h>

#define LL 12
#define BB 32
#define SS 197
#define DV 768
#define DD 512
#define CC 48
#define VV 49
#define LOSS_DEN 786432.0f

typedef unsigned short u16;
typedef unsigned int u32;
using bf16x8 = __attribute__((ext_vector_type(8))) __bf16;
using f32x4 = __attribute__((ext_vector_type(4))) float;
using u16x8 = __attribute__((ext_vector_type(8))) u16;

__device__ __forceinline__ u16 bf16h(float x) {
    u32 u = __builtin_bit_cast(u32, x);
    return (u16)((u + 0x7FFFu + ((u >> 16) & 1u)) >> 16);
}
__device__ __forceinline__ float bf2f(u16 h) {
    u32 u = ((u32)h) << 16;
    return __builtin_bit_cast(float, u);
}
__device__ __forceinline__ f32x4 mfma16(bf16x8 a, bf16x8 b, f32x4 c) {
    return __builtin_amdgcn_mfma_f32_16x16x32_bf16(a, b, c, 0, 0, 0);
}
__device__ __forceinline__ void gl_lds16(const void* g, void* s) {
    __builtin_amdgcn_global_load_lds((const __attribute__((address_space(1))) u32*)g,
                                     (__attribute__((address_space(3))) u32*)s, 16, 0, 0);
}

// ---------------------------------------------------------------------------
// Pool + bf16 hi/lo split of X
__global__ __launch_bounds__(256) void pool_split(const float* __restrict__ feats,
                                                  u16* __restrict__ Xh, u16* __restrict__ Xl) {
    int row = blockIdx.x;
    int t = threadIdx.x;
    int v = row % VV;
    int lb = row / VV;
    const float* f = feats + (size_t)lb * SS * DV;
    for (int d = t; d < DV; d += 256) {
        float val;
        if (v == 0) {
            val = f[d];
        } else {
            int i = v - 1;
            int s = (i * 196) / 48;
            int e = ((i + 1) * 196 + 47) / 48;
            float acc = 0.0f;
            for (int j = s; j < e; ++j) acc += f[(size_t)(1 + j) * DV + d];
            val = acc / (float)(e - s);
        }
        u16 h = bf16h(val);
        Xh[(size_t)row * DV + d] = h;
        Xl[(size_t)row * DV + d] = bf16h(val - bf2f(h));
    }
}

// Combined weight splits
#define NL (512 * 768)
#define NG (512 * 1536)
#define NU (512 * 1024)
__global__ __launch_bounds__(256) void wsplit_all(const float* __restrict__ Wl,
                                                  const float* __restrict__ Wg,
                                                  const float* __restrict__ Wu,
                                                  u16* Wlh, u16* Wll, u16* Wgh, u16* Wgl,
                                                  u16* Wuh, u16* Wul) {
    int i = blockIdx.x * 256 + threadIdx.x;
    float v;
    u16 *ph, *pl;
    int j;
    if (i < NL) { v = Wl[i]; ph = Wlh; pl = Wll; j = i; }
    else if (i < NL + NG) { j = i - NL; v = Wg[j]; ph = Wgh; pl = Wgl; }
    else { j = i - NL - NG; v = Wu[j]; ph = Wuh; pl = Wul; }
    u16 hh = bf16h(v);
    ph[j] = hh;
    pl[j] = bf16h(v - bf2f(hh));
}

// ---------------------------------------------------------------------------
// Generic f32 GEMM: C[m,n] = sum_k A[m,k]*W[n*wstride+k] + bias[n]; C stride 512.
__global__ __launch_bounds__(256) void gemm_f32(const float* __restrict__ A, int lda,
                                                const float* __restrict__ W, int wstride, int K,
                                                const float* __restrict__ bias,
                                                float* __restrict__ Cout) {
    __shared__ float As[32][65];
    __shared__ float Bs[32][65];
    int t = threadIdx.x;
    int m0 = blockIdx.x * 64;
    int n0 = blockIdx.y * 64;
    int r = t >> 2;
    int kc = (t & 3) * 8;
    int tx = t & 15, ty = t >> 4;
    float acc[4][4] = {};
    for (int k0 = 0; k0 < K; k0 += 32) {
        const float4* pa = (const float4*)(A + (size_t)(m0 + r) * lda + k0 + kc);
        float4 a0 = pa[0], a1 = pa[1];
        const float4* pw = (const float4*)(W + (size_t)(n0 + r) * wstride + k0 + kc);
        float4 w0 = pw[0], w1 = pw[1];
        As[kc + 0][r] = a0.x; As[kc + 1][r] = a0.y; As[kc + 2][r] = a0.z; As[kc + 3][r] = a0.w;
        As[kc + 4][r] = a1.x; As[kc + 5][r] = a1.y; As[kc + 6][r] = a1.z; As[kc + 7][r] = a1.w;
        Bs[kc + 0][r] = w0.x; Bs[kc + 1][r] = w0.y; Bs[kc + 2][r] = w0.z; Bs[kc + 3][r] = w0.w;
        Bs[kc + 4][r] = w1.x; Bs[kc + 5][r] = w1.y; Bs[kc + 6][r] = w1.z; Bs[kc + 7][r] = w1.w;
        __syncthreads();
#pragma unroll
        for (int kk = 0; kk < 32; ++kk) {
            float a[4], b[4];
#pragma unroll
            for (int i = 0; i < 4; ++i) { a[i] = As[kk][ty * 4 + i]; b[i] = Bs[kk][tx * 4 + i]; }
#pragma unroll
            for (int i = 0; i < 4; ++i)
#pragma unroll
                for (int j = 0; j < 4; ++j) acc[i][j] += a[i] * b[j];
        }
        __syncthreads();
    }
#pragma unroll
    for (int i = 0; i < 4; ++i) {
        int m = m0 + ty * 4 + i;
#pragma unroll
        for (int j = 0; j < 4; ++j) {
            int n = n0 + tx * 4 + j;
            Cout[(size_t)m * DD + n] = acc[i][j] + (bias ? bias[n] : 0.0f);
        }
    }
}

// ---------------------------------------------------------------------------
// vt = X @ W_lin.T + b_lin  (bf16x3 MFMA), emits bf16 hi/lo planes.
__global__ __launch_bounds__(256, 2) void vt_gemm(const u16* __restrict__ Xh, const u16* __restrict__ Xl,
                                                  const u16* __restrict__ Wh, const u16* __restrict__ Wl,
                                                  const float* __restrict__ bias,
                                                  u16* __restrict__ vthp, u16* __restrict__ vtlp) {
    __shared__ u16 sm[24576];
    int tid = threadIdx.x;
    int w = tid >> 6, l = tid & 63, lr = l & 15, ls = l >> 4;
    int m0 = blockIdx.x * 128, n0 = blockIdx.y * 64;
    f32x4 acc[2][4];
#pragma unroll
    for (int i = 0; i < 2; ++i)
#pragma unroll
        for (int j = 0; j < 4; ++j) acc[i][j] = f32x4{0.f, 0.f, 0.f, 0.f};

    auto stage = [&](u16* dst, int k0) {
#pragma unroll
        for (int is = 0; is < 6; ++is) {
            int q = is * 256 + tid;
            const u16* src;
            int off;
            if (is < 2)      { int qr = q;        int row = qr >> 2, sl = qr & 3; src = Xh + (size_t)(m0 + row) * DV + k0 + ((sl ^ ((row >> 1) & 3)) << 3); off = qr * 8; }
            else if (is < 4) { int qr = q - 512;  int row = qr >> 2, sl = qr & 3; src = Xl + (size_t)(m0 + row) * DV + k0 + ((sl ^ ((row >> 1) & 3)) << 3); off = 4096 + qr * 8; }
            else if (is < 5) { int qr = q - 1024; int row = qr >> 2, sl = qr & 3; src = Wh + (size_t)(n0 + row) * DV + k0 + ((sl ^ ((row >> 1) & 3)) << 3); off = 8192 + qr * 8; }
            else             { int qr = q - 1280; int row = qr >> 2, sl = qr & 3; src = Wl + (size_t)(n0 + row) * DV + k0 + ((sl ^ ((row >> 1) & 3)) << 3); off = 10240 + qr * 8; }
            gl_lds16(src, dst + off);
        }
    };

    stage(sm, 0);
    __syncthreads();
    for (int t = 0; t < 24; ++t) {
        u16* cur = sm + ((t & 1) ? 12288 : 0);
        u16* nxt = sm + ((t & 1) ? 0 : 12288);
        if (t + 1 < 24) stage(nxt, (t + 1) * 32);
        bf16x8 ah[2], al2[2], bh[4], bl2[4];
#pragma unroll
        for (int rf = 0; rf < 2; ++rf) {
            int row = 32 * w + 16 * rf + lr;
            int ro = row * 32 + ((ls ^ ((row >> 1) & 3)) << 3);
            ah[rf] = *(const bf16x8*)(cur + ro);
            al2[rf] = *(const bf16x8*)(cur + 4096 + ro);
        }
#pragma unroll
        for (int cf = 0; cf < 4; ++cf) {
            int n = 16 * cf + lr;
            int no = n * 32 + ((ls ^ ((n >> 1) & 3)) << 3);
            bh[cf] = *(const bf16x8*)(cur + 8192 + no);
            bl2[cf] = *(const bf16x8*)(cur + 10240 + no);
        }
#pragma unroll
        for (int rf = 0; rf < 2; ++rf)
#pragma unroll
            for (int cf = 0; cf < 4; ++cf) {
                acc[rf][cf] = mfma16(ah[rf], bh[cf], acc[rf][cf]);
                acc[rf][cf] = mfma16(ah[rf], bl2[cf], acc[rf][cf]);
                acc[rf][cf] = mfma16(al2[rf], bh[cf], acc[rf][cf]);
            }
        __syncthreads();
    }
#pragma unroll
    for (int rf = 0; rf < 2; ++rf)
#pragma unroll
        for (int cf = 0; cf < 4; ++cf)
#pragma unroll
            for (int r = 0; r < 4; ++r) {
                int row = m0 + 32 * w + 16 * rf + 4 * ls + r;
                int col = n0 + 16 * cf + lr;
                float v = acc[rf][cf][r] + bias[col];
                size_t o = (size_t)row * DD + col;
                u16 hh = bf16h(v);
                vthp[o] = hh;
                vtlp[o] = bf16h(v - bf2f(hh));
            }
}

// ---------------------------------------------------------------------------
__global__ __launch_bounds__(256) void init_q_loss(const float* __restrict__ ce,
                                                   u16* __restrict__ qh, u16* __restrict__ ql,
                                                   float* __restrict__ loss) {
    int i = blockIdx.x * 256 + threadIdx.x;
    float v = ce[i % (CC * DD)];
    u16 hh = bf16h(v);
    qh[i] = hh;
    ql[i] = bf16h(v - bf2f(hh));
    if (i == 0) loss[0] = 0.0f;
}

// ---------------------------------------------------------------------------
// Combined launch: blocks 0..191 = attention (4 waves x 2 q-rows each);
// blocks 192..383 = q-part GEMM: qg = q@Wg2.T, qu = q@Wu2.T (bf16x3, K=512).
__global__ __launch_bounds__(256, 2) void attn_qpart(
    const u16* __restrict__ qh, const u16* __restrict__ ql,
    const u16* __restrict__ vthL, const u16* __restrict__ vtlL,
    float* __restrict__ fcur, const float* __restrict__ fprev,
    u16* __restrict__ fh, u16* __restrict__ fl,
    float* __restrict__ loss, int do_loss,
    const u16* __restrict__ Wgh, const u16* __restrict__ Wgl,
    const u16* __restrict__ Wuh, const u16* __restrict__ Wul,
    float* __restrict__ qg, float* __restrict__ qu) {
    __shared__ u16 sm[24576];
    int tid = threadIdx.x;
    if (blockIdx.x < 192) {
        // ---------------- attention ----------------
        int wgid = blockIdx.x * 4 + (tid >> 6);
        int lane = tid & 63;
        int b = wgid / 24;
        int r0 = b * CC + (wgid % 24) * 2;
        size_t o0 = (size_t)r0 * DD + lane * 8;
        u16x8 h0 = *(const u16x8*)(qh + o0), g0 = *(const u16x8*)(ql + o0);
        u16x8 h1 = *(const u16x8*)(qh + o0 + DD), g1 = *(const u16x8*)(ql + o0 + DD);
        float q0v[8], q1v[8];
#pragma unroll
        for (int j = 0; j < 8; ++j) {
            q0v[j] = bf2f(h0[j]) + bf2f(g0[j]);
            q1v[j] = bf2f(h1[j]) + bf2f(g1[j]);
        }
        const u16* vh = vthL + (size_t)b * VV * DD + lane * 8;
        const u16* vl = vtlL + (size_t)b * VV * DD + lane * 8;
        float m0 = -3e38f, m1 = -3e38f, s0 = 0.f, s1 = 0.f;
        float a0[8] = {}, a1[8] = {};
        for (int v = 0; v < VV; ++v) {
            u16x8 rh = *(const u16x8*)(vh + v * DD);
            u16x8 rl = *(const u16x8*)(vl + v * DD);
            float rv[8];
#pragma unroll
            for (int j = 0; j < 8; ++j) rv[j] = bf2f(rh[j]) + bf2f(rl[j]);
            float p0 = 0.f, p1 = 0.f;
#pragma unroll
            for (int j = 0; j < 8; ++j) { p0 += q0v[j] * rv[j]; p1 += q1v[j] * rv[j]; }
#pragma unroll
            for (int off = 32; off > 0; off >>= 1) { p0 += __shfl_xor(p0, off); p1 += __shfl_xor(p1, off); }
            float nm0 = fmaxf(m0, p0);
            float sc0 = __expf(m0 - nm0), w0 = __expf(p0 - nm0);
            s0 = s0 * sc0 + w0;
            float nm1 = fmaxf(m1, p1);
            float sc1 = __expf(m1 - nm1), w1 = __expf(p1 - nm1);
            s1 = s1 * sc1 + w1;
#pragma unroll
            for (int j = 0; j < 8; ++j) {
                a0[j] = a0[j] * sc0 + w0 * rv[j];
                a1[j] = a1[j] * sc1 + w1 * rv[j];
            }
            m0 = nm0;
            m1 = nm1;
        }
        float inv0 = 1.0f / s0, inv1 = 1.0f / s1;
        float d2 = 0.f;
        float f0v[8], f1v[8];
        u16x8 oh0, ol0, oh1, ol1;
#pragma unroll
        for (int j = 0; j < 8; ++j) {
            float f = a0[j] * inv0;
            f0v[j] = f;
            u16 hh = bf16h(f);
            oh0[j] = hh;
            ol0[j] = bf16h(f - bf2f(hh));
            float f2 = a1[j] * inv1;
            f1v[j] = f2;
            u16 h2 = bf16h(f2);
            oh1[j] = h2;
            ol1[j] = bf16h(f2 - bf2f(h2));
        }
        *(float4*)(fcur + o0) = float4{f0v[0], f0v[1], f0v[2], f0v[3]};
        *(float4*)(fcur + o0 + 4) = float4{f0v[4], f0v[5], f0v[6], f0v[7]};
        *(float4*)(fcur + o0 + DD) = float4{f1v[0], f1v[1], f1v[2], f1v[3]};
        *(float4*)(fcur + o0 + DD + 4) = float4{f1v[4], f1v[5], f1v[6], f1v[7]};
        *(u16x8*)(fh + o0) = oh0;
        *(u16x8*)(fl + o0) = ol0;
        *(u16x8*)(fh + o0 + DD) = oh1;
        *(u16x8*)(fl + o0 + DD) = ol1;
        if (do_loss) {
#pragma unroll
            for (int j = 0; j < 8; ++j) {
                float d = f0v[j] - fprev[o0 + j];
                d2 += d * d;
                float e = f1v[j] - fprev[o0 + DD + j];
                d2 += e * e;
            }
#pragma unroll
            for (int off = 32; off > 0; off >>= 1) d2 += __shfl_xor(d2, off);
            if (lane == 0) atomicAdd(loss, d2);
        }
    } else {
        // ---------------- q-part GEMM ----------------
        int tb = blockIdx.x - 192;
        int w = tid >> 6, l = tid & 63, lr = l & 15, ls = l >> 4;
        int wr = w >> 1, wc = w & 1;
        int m0 = (tb >> 3) * 64, n0 = (tb & 7) * 64;
        f32x4 ag[2][2], au[2][2];
#pragma unroll
        for (int i = 0; i < 2; ++i)
#pragma unroll
            for (int j = 0; j < 2; ++j) { ag[i][j] = f32x4{0.f, 0.f, 0.f, 0.f}; au[i][j] = f32x4{0.f, 0.f, 0.f, 0.f}; }

        auto stage = [&](u16* dst, int k0) {
            int q = tid, row = q >> 2, sl = q & 3;
            int kk = ((sl ^ ((row >> 1) & 3)) << 3);
            int mrow = m0 + row, nrow = n0 + row;
            gl_lds16(qh + (size_t)mrow * DD + k0 + kk, dst + q * 8);
            gl_lds16(ql + (size_t)mrow * DD + k0 + kk, dst + 2048 + q * 8);
            gl_lds16(Wgh + (size_t)nrow * 1536 + 512 + k0 + kk, dst + 4096 + q * 8);
            gl_lds16(Wgl + (size_t)nrow * 1536 + 512 + k0 + kk, dst + 6144 + q * 8);
            gl_lds16(Wuh + (size_t)nrow * 1024 + 512 + k0 + kk, dst + 8192 + q * 8);
            gl_lds16(Wul + (size_t)nrow * 1024 + 512 + k0 + kk, dst + 10240 + q * 8);
        };

        stage(sm, 0);
        __syncthreads();
        for (int t = 0; t < 16; ++t) {
            u16* cur = sm + ((t & 1) ? 12288 : 0);
            u16* nxt = sm + ((t & 1) ? 0 : 12288);
            if (t + 1 < 16) stage(nxt, (t + 1) * 32);
            bf16x8 a_h[2], a_l[2], g_h[2], g_l[2], u_h[2], u_l[2];
#pragma unroll
            for (int rf = 0; rf < 2; ++rf) {
                int arow = 32 * wr + 16 * rf + lr;
                int ao = arow * 32 + ((ls ^ ((arow >> 1) & 3)) << 3);
                a_h[rf] = *(const bf16x8*)(cur + ao);
                a_l[rf] = *(const bf16x8*)(cur + 2048 + ao);
            }
#pragma unroll
            for (int cf = 0; cf < 2; ++cf) {
                int n = 32 * wc + 16 * cf + lr;
                int no = n * 32 + ((ls ^ ((n >> 1) & 3)) << 3);
                g_h[cf] = *(const bf16x8*)(cur + 4096 + no);
                g_l[cf] = *(const bf16x8*)(cur + 6144 + no);
                u_h[cf] = *(const bf16x8*)(cur + 8192 + no);
                u_l[cf] = *(const bf16x8*)(cur + 10240 + no);
            }
#pragma unroll
            for (int rf = 0; rf < 2; ++rf)
#pragma unroll
                for (int cf = 0; cf < 2; ++cf) {
                    ag[rf][cf] = mfma16(a_h[rf], g_h[cf], ag[rf][cf]);
                    ag[rf][cf] = mfma16(a_h[rf], g_l[cf], ag[rf][cf]);
                    ag[rf][cf] = mfma16(a_l[rf], g_h[cf], ag[rf][cf]);
                    au[rf][cf] = mfma16(a_h[rf], u_h[cf], au[rf][cf]);
                    au[rf][cf] = mfma16(a_h[rf], u_l[cf], au[rf][cf]);
                    au[rf][cf] = mfma16(a_l[rf], u_h[cf], au[rf][cf]);
                }
            __syncthreads();
        }
#pragma unroll
        for (int rf = 0; rf < 2; ++rf)
#pragma unroll
            for (int cf = 0; cf < 2; ++cf)
#pragma unroll
                for (int r = 0; r < 4; ++r) {
                    int row = m0 + 32 * wr + 16 * rf + 4 * ls + r;
                    int col = n0 + 32 * wc + 16 * cf + lr;
                    size_t o = (size_t)row * DD + col;
                    qg[o] = ag[rf][cf][r];
                    qu[o] = au[rf][cf][r];
                }
    }
}

// ---------------------------------------------------------------------------
// fuse-part GEMM + combine: gate = sigmoid(fuse@Wg1 + qg + Cg), upd = tanh(fuse@Wu1 + qu + bu)
// qout = g*q + (1-g)*u -> planes.
__global__ __launch_bounds__(256, 2) void fusepart(
    const u16* __restrict__ fhp, const u16* __restrict__ flp,
    const u16* __restrict__ qhp, const u16* __restrict__ qlp,
    const u16* __restrict__ Wgh, const u16* __restrict__ Wgl,
    const u16* __restrict__ Wuh, const u16* __restrict__ Wul,
    const float* __restrict__ qg, const float* __restrict__ qu,
    const float* __restrict__ CgL, const float* __restrict__ bu,
    u16* __restrict__ qoh, u16* __restrict__ qol) {
    __shared__ u16 sm[24576];
    int tid = threadIdx.x;
    int w = tid >> 6, l = tid & 63, lr = l & 15, ls = l >> 4;
    int wr = w >> 1, wc = w & 1;
    int m0 = (blockIdx.x >> 3) * 64, n0 = (blockIdx.x & 7) * 64;
    f32x4 ag[2][2], au[2][2];
#pragma unroll
    for (int i = 0; i < 2; ++i)
#pragma unroll
        for (int j = 0; j < 2; ++j) { ag[i][j] = f32x4{0.f, 0.f, 0.f, 0.f}; au[i][j] = f32x4{0.f, 0.f, 0.f, 0.f}; }

    auto stage = [&](u16* dst, int k0) {
        int q = tid, row = q >> 2, sl = q & 3;
        int kk = ((sl ^ ((row >> 1) & 3)) << 3);
        int mrow = m0 + row, nrow = n0 + row;
        gl_lds16(fhp + (size_t)mrow * DD + k0 + kk, dst + q * 8);
        gl_lds16(flp + (size_t)mrow * DD + k0 + kk, dst + 2048 + q * 8);
        gl_lds16(Wgh + (size_t)nrow * 1536 + k0 + kk, dst + 4096 + q * 8);
        gl_lds16(Wgl + (size_t)nrow * 1536 + k0 + kk, dst + 6144 + q * 8);
        gl_lds16(Wuh + (size_t)nrow * 1024 + k0 + kk, dst + 8192 + q * 8);
        gl_lds16(Wul + (size_t)nrow * 1024 + k0 + kk, dst + 10240 + q * 8);
    };

    stage(sm, 0);
    __syncthreads();
    for (int t = 0; t < 16; ++t) {
        u16* cur = sm + ((t & 1) ? 12288 : 0);
        u16* nxt = sm + ((t & 1) ? 0 : 12288);
        if (t + 1 < 16) stage(nxt, (t + 1) * 32);
        bf16x8 a_h[2], a_l[2], g_h[2], g_l[2], u_h[2], u_l[2];
#pragma unroll
        for (int rf = 0; rf < 2; ++rf) {
            int arow = 32 * wr + 16 * rf + lr;
            int ao = arow * 32 + ((ls ^ ((arow >> 1) & 3)) << 3);
            a_h[rf] = *(const bf16x8*)(cur + ao);
            a_l[rf] = *(const bf16x8*)(cur + 2048 + ao);
        }
#pragma unroll
        for (int cf = 0; cf < 2; ++cf) {
            int n = 32 * wc + 16 * cf + lr;
            int no = n * 32 + ((ls ^ ((n >> 1) & 3)) << 3);
            g_h[cf] = *(const bf16x8*)(cur + 4096 + no);
            g_l[cf] = *(const bf16x8*)(cur + 6144 + no);
            u_h[cf] = *(const bf16x8*)(cur + 8192 + no);
            u_l[cf] = *(const bf16x8*)(cur + 10240 + no);
        }
#pragma unroll
        for (int rf = 0; rf < 2; ++rf)
#pragma unroll
            for (int cf = 0; cf < 2; ++cf) {
                ag[rf][cf] = mfma16(a_h[rf], g_h[cf], ag[rf][cf]);
                ag[rf][cf] = mfma16(a_h[rf], g_l[cf], ag[rf][cf]);
                ag[rf][cf] = mfma16(a_l[rf], g_h[cf], ag[rf][cf]);
                au[rf][cf] = mfma16(a_h[rf], u_h[cf], au[rf][cf]);
                au[rf][cf] = mfma16(a_h[rf], u_l[cf], au[rf][cf]);
                au[rf][cf] = mfma16(a_l[rf], u_h[cf], au[rf][cf]);
            }
        __syncthreads();
    }
#pragma unroll
    for (int rf = 0; rf < 2; ++rf)
#pragma unroll
        for (int cf = 0; cf < 2; ++cf)
#pragma unroll
            for (int r = 0; r < 4; ++r) {
                int row = m0 + 32 * wr + 16 * rf + 4 * ls + r;
                int col = n0 + 32 * wc + 16 * cf + lr;
                int b = row / CC;
                size_t o = (size_t)row * DD + col;
                float gpre = ag[rf][cf][r] + qg[o] + CgL[(size_t)b * DD + col];
                float upre = au[rf][cf][r] + qu[o] + bu[col];
                float g = 1.0f / (1.0f + __expf(-gpre));
                float u = tanhf(upre);
                float qv = bf2f(qhp[o]) + bf2f(qlp[o]);
                float qo = g * qv + (1.0f - g) * u;
                u16 hh = bf16h(qo);
                qoh[o] = hh;
                qol[o] = bf16h(qo - bf2f(hh));
            }
}

// ---------------------------------------------------------------------------
__global__ __launch_bounds__(256) void final_kernel(const float* __restrict__ fuse_last,
                                                    const float* __restrict__ ce,
                                                    const float* __restrict__ W_cls,
                                                    const float* __restrict__ b_cls,
                                                    const float* __restrict__ loss_acc,
                                                    float* __restrict__ out) {
    int b = blockIdx.x;
    int t = threadIdx.x;
    int w = t >> 6, lane = t & 63;
    __shared__ float invn[CC];
    __shared__ float img[CC];
    const float* fb = fuse_last + (size_t)b * CC * DD;
    for (int c = w; c < CC; c += 4) {
        const float* fr = fb + (size_t)c * DD + lane * 8;
        float4 a0 = *(const float4*)fr;
        float4 a1 = *(const float4*)(fr + 4);
        float ss = a0.x * a0.x + a0.y * a0.y + a0.z * a0.z + a0.w * a0.w +
                   a1.x * a1.x + a1.y * a1.y + a1.z * a1.z + a1.w * a1.w;
#pragma unroll
        for (int off = 32; off > 0; off >>= 1) ss += __shfl_xor(ss, off);
        if (lane == 0) invn[c] = 1.0f / fmaxf(sqrtf(ss), 1e-12f);
    }
    __syncthreads();
    for (int g = w; g < CC; g += 4) {
        int k = g / 6;
        const float* ar = ce + (size_t)g * DD + lane * 8;
        float4 c0 = *(const float4*)ar;
        float4 c1 = *(const float4*)(ar + 4);
        float av[8] = {c0.x, c0.y, c0.z, c0.w, c1.x, c1.y, c1.z, c1.w};
        float accp = 0.0f;
        for (int p = 0; p < 6; ++p) {
            int row = k * 6 + p;
            const float* fr = fb + (size_t)row * DD + lane * 8;
            float4 f0 = *(const float4*)fr;
            float4 f1 = *(const float4*)(fr + 4);
            float fv[8] = {f0.x, f0.y, f0.z, f0.w, f1.x, f1.y, f1.z, f1.w};
            float d = 0.0f;
#pragma unroll
            for (int j = 0; j < 8; ++j) d += fv[j] * av[j];
            accp += d * invn[row];
        }
#pragma unroll
        for (int off = 32; off > 0; off >>= 1) accp += __shfl_xor(accp, off);
        if (lane == 0) img[g] = accp * (100.0f / 6.0f);
    }
    __syncthreads();
    if (t < CC) out[BB * 7 + b * CC + t] = img[t];
    if (t < 7) {
        float sacc = b_cls[t];
        for (int c = 0; c < CC; ++c) sacc += img[c] * W_cls[t * CC + c];
        out[b * 7 + t] = sacc;
    }
    if (b == 0 && t == 0) out[BB * 7 + BB * CC] = loss_acc[0] * (1.0f / LOSS_DEN);
}

// ---------------------------------------------------------------------------
extern "C" void kernel_launch(void* const* d_in, const int* in_sizes, int n_in,
                              void* d_out, int out_size, void* d_ws, size_t ws_size,
                              hipStream_t stream) {
    const float* feats = (const float*)d_in[0];
    const float* ce = (const float*)d_in[1];
    const float* W_lin = (const float*)d_in[2];
    const float* b_lin = (const float*)d_in[3];
    const float* W_proj = (const float*)d_in[4];
    const float* W_gate = (const float*)d_in[5];
    const float* b_gate = (const float*)d_in[6];
    const float* W_upd = (const float*)d_in[7];
    const float* b_upd = (const float*)d_in[8];
    const float* W_cls = (const float*)d_in[9];
    const float* b_cls = (const float*)d_in[10];
    float* out = (float*)d_out;

    char* base = (char*)d_ws;
    size_t off = 0;
    auto alloc = [&](size_t bytes) -> char* {
        char* r = base + off;
        off += (bytes + 255) & ~(size_t)255;
        return r;
    };
    u16* Xh = (u16*)alloc((size_t)LL * BB * VV * DV * 2);
    u16* Xl = (u16*)alloc((size_t)LL * BB * VV * DV * 2);
    u16* vth = (u16*)alloc((size_t)LL * BB * VV * DD * 2);
    u16* vtl = (u16*)alloc((size_t)LL * BB * VV * DD * 2);
    float* ctx = (float*)alloc((size_t)LL * BB * DD * 4);
    float* Cg = (float*)alloc((size_t)LL * BB * DD * 4);
    float* fbuf0 = (float*)alloc((size_t)BB * CC * DD * 4);
    float* fbuf1 = (float*)alloc((size_t)BB * CC * DD * 4);
    float* qg = (float*)alloc((size_t)BB * CC * DD * 4);
    float* qu = (float*)alloc((size_t)BB * CC * DD * 4);
    float* loss = (float*)alloc(256);
    u16* Wlh = (u16*)alloc((size_t)NL * 2);
    u16* Wll = (u16*)alloc((size_t)NL * 2);
    u16* Wgh = (u16*)alloc((size_t)NG * 2);
    u16* Wgl = (u16*)alloc((size_t)NG * 2);
    u16* Wuh = (u16*)alloc((size_t)NU * 2);
    u16* Wul = (u16*)alloc((size_t)NU * 2);
    u16* fh = (u16*)alloc((size_t)BB * CC * DD * 2);
    u16* fl = (u16*)alloc((size_t)BB * CC * DD * 2);
    u16* qah = (u16*)alloc((size_t)BB * CC * DD * 2);
    u16* qal = (u16*)alloc((size_t)BB * CC * DD * 2);
    u16* qbh = (u16*)alloc((size_t)BB * CC * DD * 2);
    u16* qbl = (u16*)alloc((size_t)BB * CC * DD * 2);
    u16* qph[2] = {qah, qbh};
    u16* qpl[2] = {qal, qbl};

    // ---- precompute ----
    pool_split<<<LL * BB * VV, 256, 0, stream>>>(feats, Xh, Xl);
    wsplit_all<<<(NL + NG + NU) / 256, 256, 0, stream>>>(W_lin, W_gate, W_upd, Wlh, Wll, Wgh, Wgl, Wuh, Wul);
    {
        dim3 g(LL * BB / 64, DD / 64);
        gemm_f32<<<g, 256, 0, stream>>>(feats, SS * DV, W_proj, DV, DV, nullptr, ctx);
        gemm_f32<<<g, 256, 0, stream>>>(ctx, DD, W_gate + 1024, 1536, DD, b_gate, Cg);
    }
    init_q_loss<<<(BB * CC * DD) / 256, 256, 0, stream>>>(ce, qah, qal, loss);
    {
        dim3 g(147, 8);
        vt_gemm<<<g, 256, 0, stream>>>(Xh, Xl, Wlh, Wll, b_lin, vth, vtl);
    }

    // ---- 12-layer scan ----
    int qc = 0;
    for (int l = 0; l < LL; ++l) {
        float* fcur = (l & 1) ? fbuf1 : fbuf0;
        const float* fprev = (l & 1) ? fbuf0 : fbuf1;
        int grid = (l < LL - 1) ? 384 : 192;
        attn_qpart<<<grid, 256, 0, stream>>>(qph[qc], qpl[qc],
                                             vth + (size_t)l * BB * VV * DD, vtl + (size_t)l * BB * VV * DD,
                                             fcur, fprev, fh, fl, loss, l > 0 ? 1 : 0,
                                             Wgh, Wgl, Wuh, Wul, qg, qu);
        if (l < LL - 1) {
            fusepart<<<192, 256, 0, stream>>>(fh, fl, qph[qc], qpl[qc],
                                              Wgh, Wgl, Wuh, Wul, qg, qu,
                                              Cg + (size_t)l * BB * DD, b_upd,
                                              qph[qc ^ 1], qpl[qc ^ 1]);
            qc ^= 1;
        }
    }

    final_kernel<<<BB, 256, 0, stream>>>((LL - 1) & 1 ? fbuf1 : fbuf0, ce, W_cls, b_cls, loss, out);
}